// Round 1
// baseline (614.831 us; speedup 1.0000x reference)
//
#include <hip/hip_runtime.h>

#define NN   100000
#define NE   1600000
#define CIN  128
#define CHID 128
#define COUT 64

#define SCAN_B 512
#define NBLK_A 196   // ceil(NN/512)

// ---------------- preprocessing ----------------

__global__ void k_zero(int* __restrict__ p, int n) {
  int i = blockIdx.x * blockDim.x + threadIdx.x;
  if (i < n) p[i] = 0;
}

__global__ void k_count(const int* __restrict__ dst, int* __restrict__ cnt) {
  int i = blockIdx.x * blockDim.x + threadIdx.x;
  if (i < NE) atomicAdd(&cnt[dst[i]], 1);
}

// exclusive scan, phase A: per-block scan of 512 elements
__global__ void k_scan_a(const int* __restrict__ cnt, int* __restrict__ ex,
                         int* __restrict__ bs) {
  __shared__ int s[SCAN_B];
  int t = threadIdx.x;
  int g = blockIdx.x * SCAN_B + t;
  int v = (g < NN) ? cnt[g] : 0;
  s[t] = v;
  __syncthreads();
  for (int off = 1; off < SCAN_B; off <<= 1) {
    int u = (t >= off) ? s[t - off] : 0;
    __syncthreads();
    s[t] += u;
    __syncthreads();
  }
  if (g < NN) ex[g] = s[t] - v;           // exclusive value (block-local)
  if (t == SCAN_B - 1) bs[blockIdx.x] = s[t];
}

// phase B: scan the 196 block sums (single block)
__global__ void k_scan_b(int* __restrict__ bs) {
  __shared__ int s[256];
  int t = threadIdx.x;
  int v = (t < NBLK_A) ? bs[t] : 0;
  s[t] = v;
  __syncthreads();
  for (int off = 1; off < 256; off <<= 1) {
    int u = (t >= off) ? s[t - off] : 0;
    __syncthreads();
    s[t] += u;
    __syncthreads();
  }
  if (t < NBLK_A) bs[t] = s[t] - v;       // exclusive
}

// phase C: add block offsets; also init cursor and dinv; set row_start[NN]=NE
__global__ void k_scan_c(int* __restrict__ ex, const int* __restrict__ bs,
                         int* __restrict__ cursor, const int* __restrict__ cnt,
                         float* __restrict__ dinv) {
  int g = blockIdx.x * SCAN_B + threadIdx.x;
  if (g < NN) {
    int v = ex[g] + bs[blockIdx.x];
    ex[g] = v;
    cursor[g] = v;
    dinv[g] = rsqrtf((float)cnt[g] + 1.0f);
  } else if (g == NN) {
    ex[NN] = NE;
  }
}

__global__ void k_fill(const int* __restrict__ src, const int* __restrict__ dst,
                       int* __restrict__ cursor, int* __restrict__ csr) {
  int i = blockIdx.x * blockDim.x + threadIdx.x;
  if (i < NE) {
    int p = atomicAdd(&cursor[dst[i]], 1);
    csr[p] = src[i];
  }
}

// ---------------- GEMM 1: H1[N,128] = X[N,128] @ W1[128,128] ----------------
// 64 rows/block, 256 threads, thread tile 4x8, K chunked by 64.
__global__ __launch_bounds__(256) void k_gemm1(const float* __restrict__ X,
                                               const float* __restrict__ W,
                                               float* __restrict__ H) {
  __shared__ float Ws[64 * CHID];   // 32 KB, rows kb..kb+63
  __shared__ float Xs[64 * 65];     // 16.6 KB, transposed [k][r], pad to 65
  int tid = threadIdx.x;
  int rowBase = blockIdx.x * 64;
  int tx = tid & 15, ty = tid >> 4;
  int c0 = tx * 8, r0 = ty * 4;

  float acc[4][8];
#pragma unroll
  for (int i = 0; i < 4; i++)
#pragma unroll
    for (int j = 0; j < 8; j++) acc[i][j] = 0.f;

  for (int kb = 0; kb < CIN; kb += 64) {
    __syncthreads();
    // stage W chunk [64][128]
    for (int i = tid; i < 64 * 32; i += 256) {
      int r = i >> 5, c4 = i & 31;
      ((float4*)Ws)[i] = ((const float4*)W)[(size_t)(kb + r) * 32 + c4];
    }
    // stage X chunk transposed: Xs[k][r]
    for (int i = tid; i < 64 * 16; i += 256) {
      int r = i >> 4;
      int kc = (i & 15) << 2;
      int gr = rowBase + r;
      float4 v = make_float4(0.f, 0.f, 0.f, 0.f);
      if (gr < NN) v = *(const float4*)(X + (size_t)gr * CIN + kb + kc);
      Xs[(kc + 0) * 65 + r] = v.x;
      Xs[(kc + 1) * 65 + r] = v.y;
      Xs[(kc + 2) * 65 + r] = v.z;
      Xs[(kc + 3) * 65 + r] = v.w;
    }
    __syncthreads();
#pragma unroll 4
    for (int k = 0; k < 64; k++) {
      float xv[4];
#pragma unroll
      for (int i = 0; i < 4; i++) xv[i] = Xs[k * 65 + r0 + i];
      float4 w0 = *(const float4*)&Ws[k * CHID + c0];
      float4 w1 = *(const float4*)&Ws[k * CHID + c0 + 4];
      float wv[8] = {w0.x, w0.y, w0.z, w0.w, w1.x, w1.y, w1.z, w1.w};
#pragma unroll
      for (int i = 0; i < 4; i++)
#pragma unroll
        for (int j = 0; j < 8; j++) acc[i][j] = fmaf(xv[i], wv[j], acc[i][j]);
    }
  }

#pragma unroll
  for (int i = 0; i < 4; i++) {
    int gr = rowBase + r0 + i;
    if (gr < NN) {
      float4 a = make_float4(acc[i][0], acc[i][1], acc[i][2], acc[i][3]);
      float4 b = make_float4(acc[i][4], acc[i][5], acc[i][6], acc[i][7]);
      *(float4*)(H + (size_t)gr * CHID + c0) = a;
      *(float4*)(H + (size_t)gr * CHID + c0 + 4) = b;
    }
  }
}

// ---------------- GEMM 2: H2[N,64] = O1[N,128] @ W2[128,64] ----------------
// 128 rows/block, 256 threads, thread tile 4x8, K chunked by 64.
__global__ __launch_bounds__(256) void k_gemm2(const float* __restrict__ X,
                                               const float* __restrict__ W,
                                               float* __restrict__ H) {
  __shared__ float Ws[64 * COUT];    // 16 KB
  __shared__ float Xs[64 * 129];     // 33 KB, transposed [k][r]
  int tid = threadIdx.x;
  int rowBase = blockIdx.x * 128;
  int tx = tid & 7, ty = tid >> 3;
  int c0 = tx * 8, r0 = ty * 4;

  float acc[4][8];
#pragma unroll
  for (int i = 0; i < 4; i++)
#pragma unroll
    for (int j = 0; j < 8; j++) acc[i][j] = 0.f;

  for (int kb = 0; kb < CHID; kb += 64) {
    __syncthreads();
    // stage W chunk [64][64]
    for (int i = tid; i < 64 * 16; i += 256) {
      int r = i >> 4, c4 = i & 15;
      ((float4*)Ws)[i] = ((const float4*)W)[(size_t)(kb + r) * 16 + c4];
    }
    // stage X chunk transposed
    for (int i = tid; i < 128 * 16; i += 256) {
      int r = i >> 4;
      int kc = (i & 15) << 2;
      int gr = rowBase + r;
      float4 v = make_float4(0.f, 0.f, 0.f, 0.f);
      if (gr < NN) v = *(const float4*)(X + (size_t)gr * CHID + kb + kc);
      Xs[(kc + 0) * 129 + r] = v.x;
      Xs[(kc + 1) * 129 + r] = v.y;
      Xs[(kc + 2) * 129 + r] = v.z;
      Xs[(kc + 3) * 129 + r] = v.w;
    }
    __syncthreads();
#pragma unroll 4
    for (int k = 0; k < 64; k++) {
      float xv[4];
#pragma unroll
      for (int i = 0; i < 4; i++) xv[i] = Xs[k * 129 + r0 + i];
      float4 w0 = *(const float4*)&Ws[k * COUT + c0];
      float4 w1 = *(const float4*)&Ws[k * COUT + c0 + 4];
      float wv[8] = {w0.x, w0.y, w0.z, w0.w, w1.x, w1.y, w1.z, w1.w};
#pragma unroll
      for (int i = 0; i < 4; i++)
#pragma unroll
        for (int j = 0; j < 8; j++) acc[i][j] = fmaf(xv[i], wv[j], acc[i][j]);
    }
  }

#pragma unroll
  for (int i = 0; i < 4; i++) {
    int gr = rowBase + r0 + i;
    if (gr < NN) {
      float4 a = make_float4(acc[i][0], acc[i][1], acc[i][2], acc[i][3]);
      float4 b = make_float4(acc[i][4], acc[i][5], acc[i][6], acc[i][7]);
      *(float4*)(H + (size_t)gr * COUT + c0) = a;
      *(float4*)(H + (size_t)gr * COUT + c0 + 4) = b;
    }
  }
}

// ---------------- aggregation (pull, one wave per node) ----------------
// layer 1: out = relu(agg + dinv^2 * h + b), C=128, lane owns 2 channels
__global__ __launch_bounds__(256) void k_agg1(const float* __restrict__ h,
                                              const int* __restrict__ rs,
                                              const int* __restrict__ csr,
                                              const float* __restrict__ dinv,
                                              const float* __restrict__ b,
                                              float* __restrict__ o) {
  int wid = (blockIdx.x * blockDim.x + threadIdx.x) >> 6;
  int lane = threadIdx.x & 63;
  if (wid >= NN) return;
  float dn = dinv[wid];
  const float2* hp = (const float2*)h;
  float2 hn = hp[(size_t)wid * 64 + lane];
  float2 acc = make_float2(dn * dn * hn.x, dn * dn * hn.y);
  int e0 = rs[wid], e1 = rs[wid + 1];
  for (int i = e0; i < e1; i++) {
    int s = csr[i];
    float w = dinv[s] * dn;
    float2 hv = hp[(size_t)s * 64 + lane];
    acc.x = fmaf(w, hv.x, acc.x);
    acc.y = fmaf(w, hv.y, acc.y);
  }
  float2 bb = ((const float2*)b)[lane];
  ((float2*)o)[(size_t)wid * 64 + lane] =
      make_float2(fmaxf(acc.x + bb.x, 0.f), fmaxf(acc.y + bb.y, 0.f));
}

// layer 2: out = agg + dinv^2 * h + b, C=64, lane owns 1 channel
__global__ __launch_bounds__(256) void k_agg2(const float* __restrict__ h,
                                              const int* __restrict__ rs,
                                              const int* __restrict__ csr,
                                              const float* __restrict__ dinv,
                                              const float* __restrict__ b,
                                              float* __restrict__ o) {
  int wid = (blockIdx.x * blockDim.x + threadIdx.x) >> 6;
  int lane = threadIdx.x & 63;
  if (wid >= NN) return;
  float dn = dinv[wid];
  float acc = dn * dn * h[(size_t)wid * COUT + lane];
  int e0 = rs[wid], e1 = rs[wid + 1];
  for (int i = e0; i < e1; i++) {
    int s = csr[i];
    acc = fmaf(dinv[s] * dn, h[(size_t)s * COUT + lane], acc);
  }
  o[(size_t)wid * COUT + lane] = acc + b[lane];
}

// ---------------- launch ----------------

extern "C" void kernel_launch(void* const* d_in, const int* in_sizes, int n_in,
                              void* d_out, int out_size, void* d_ws, size_t ws_size,
                              hipStream_t stream) {
  const float* x  = (const float*)d_in[0];
  const int*   ei = (const int*)d_in[1];
  const float* W1 = (const float*)d_in[2];
  const float* b1 = (const float*)d_in[3];
  const float* W2 = (const float*)d_in[4];
  const float* b2 = (const float*)d_in[5];
  float* out = (float*)d_out;

  const int* esrc = ei;
  const int* edst = ei + NE;

  char* p = (char*)d_ws;
  float* h1 = (float*)p;      p += (size_t)NN * CHID * 4;   // 51.2 MB
  float* o1 = (float*)p;      p += (size_t)NN * CHID * 4;   // 51.2 MB
  int* cnt = (int*)p;         p += (size_t)NN * 4;
  int* rs  = (int*)p;         p += (size_t)(NN + 1) * 4;
  int* cursor = (int*)p;      p += (size_t)NN * 4;
  float* dinv = (float*)p;    p += (size_t)NN * 4;
  int* bs  = (int*)p;         p += (size_t)256 * 4;
  int* csr = (int*)p;         p += (size_t)NE * 4;          // 6.4 MB
  float* h2 = h1;  // alias: h1 is dead once o1 is produced

  // preprocessing: degrees, CSR
  hipLaunchKernelGGL(k_zero, dim3((NN + 255) / 256), dim3(256), 0, stream, cnt, NN);
  hipLaunchKernelGGL(k_count, dim3((NE + 255) / 256), dim3(256), 0, stream, edst, cnt);
  hipLaunchKernelGGL(k_scan_a, dim3(NBLK_A), dim3(SCAN_B), 0, stream, cnt, rs, bs);
  hipLaunchKernelGGL(k_scan_b, dim3(1), dim3(256), 0, stream, bs);
  hipLaunchKernelGGL(k_scan_c, dim3(NBLK_A), dim3(SCAN_B), 0, stream, rs, bs, cursor, cnt, dinv);
  hipLaunchKernelGGL(k_fill, dim3((NE + 255) / 256), dim3(256), 0, stream, esrc, edst, cursor, csr);

  // layer 1
  hipLaunchKernelGGL(k_gemm1, dim3((NN + 63) / 64), dim3(256), 0, stream, x, W1, h1);
  hipLaunchKernelGGL(k_agg1, dim3((NN + 3) / 4), dim3(256), 0, stream, h1, rs, csr, dinv, b1, o1);

  // layer 2
  hipLaunchKernelGGL(k_gemm2, dim3((NN + 127) / 128), dim3(256), 0, stream, o1, W2, h2);
  hipLaunchKernelGGL(k_agg2, dim3((NN + 3) / 4), dim3(256), 0, stream, h2, rs, csr, dinv, b2, out);
}

// Round 2
// 420.733 us; speedup vs baseline: 1.4613x; 1.4613x over previous
//
#include <hip/hip_runtime.h>
#include <hip/hip_fp16.h>

#define NN   100000
#define NE   1600000
#define CIN  128
#define CHID 128
#define COUT 64

#define SCAN_B 512
#define NBLK_A 196   // ceil(NN/512)

// ---------------- preprocessing ----------------

__global__ void k_zero(int* __restrict__ p, int n) {
  int i = blockIdx.x * blockDim.x + threadIdx.x;
  if (i < n) p[i] = 0;
}

__global__ void k_count(const int* __restrict__ dst, int* __restrict__ cnt) {
  int i = blockIdx.x * blockDim.x + threadIdx.x;
  if (i < NE) atomicAdd(&cnt[dst[i]], 1);
}

// exclusive scan, phase A: per-block scan of 512 elements
__global__ void k_scan_a(const int* __restrict__ cnt, int* __restrict__ ex,
                         int* __restrict__ bs) {
  __shared__ int s[SCAN_B];
  int t = threadIdx.x;
  int g = blockIdx.x * SCAN_B + t;
  int v = (g < NN) ? cnt[g] : 0;
  s[t] = v;
  __syncthreads();
  for (int off = 1; off < SCAN_B; off <<= 1) {
    int u = (t >= off) ? s[t - off] : 0;
    __syncthreads();
    s[t] += u;
    __syncthreads();
  }
  if (g < NN) ex[g] = s[t] - v;           // exclusive (block-local)
  if (t == SCAN_B - 1) bs[blockIdx.x] = s[t];
}

// phase B: scan the 196 block sums (single block)
__global__ void k_scan_b(int* __restrict__ bs) {
  __shared__ int s[256];
  int t = threadIdx.x;
  int v = (t < NBLK_A) ? bs[t] : 0;
  s[t] = v;
  __syncthreads();
  for (int off = 1; off < 256; off <<= 1) {
    int u = (t >= off) ? s[t - off] : 0;
    __syncthreads();
    s[t] += u;
    __syncthreads();
  }
  if (t < NBLK_A) bs[t] = s[t] - v;       // exclusive
}

// phase C: add block offsets; init cursor and dinv; set row_start[NN]=NE
__global__ void k_scan_c(int* __restrict__ ex, const int* __restrict__ bs,
                         int* __restrict__ cursor, const int* __restrict__ cnt,
                         float* __restrict__ dinv) {
  int g = blockIdx.x * SCAN_B + threadIdx.x;
  if (g < NN) {
    int v = ex[g] + bs[blockIdx.x];
    ex[g] = v;
    cursor[g] = v;
    dinv[g] = rsqrtf((float)cnt[g] + 1.0f);
  } else if (g == NN) {
    ex[NN] = NE;
  }
}

__global__ void k_fill(const int* __restrict__ src, const int* __restrict__ dst,
                       int* __restrict__ cursor, int* __restrict__ csr) {
  int i = blockIdx.x * blockDim.x + threadIdx.x;
  if (i < NE) {
    int p = atomicAdd(&cursor[dst[i]], 1);
    csr[p] = src[i];
  }
}

// ---------------- GEMM 1: G1[N,128] = fp16(dinv * (X @ W1)) ----------------
// 64 rows/block, 256 threads, thread tile 4x8, K chunked by 64.
__global__ __launch_bounds__(256) void k_gemm1(const float* __restrict__ X,
                                               const float* __restrict__ W,
                                               const float* __restrict__ dinv,
                                               __half* __restrict__ G) {
  __shared__ float Ws[64 * CHID];   // 32 KB
  __shared__ float Xs[64 * 65];     // 16.6 KB, transposed [k][r]
  int tid = threadIdx.x;
  int rowBase = blockIdx.x * 64;
  int tx = tid & 15, ty = tid >> 4;
  int c0 = tx * 8, r0 = ty * 4;

  float acc[4][8];
#pragma unroll
  for (int i = 0; i < 4; i++)
#pragma unroll
    for (int j = 0; j < 8; j++) acc[i][j] = 0.f;

  for (int kb = 0; kb < CIN; kb += 64) {
    __syncthreads();
    for (int i = tid; i < 64 * 32; i += 256) {
      int r = i >> 5, c4 = i & 31;
      ((float4*)Ws)[i] = ((const float4*)W)[(size_t)(kb + r) * 32 + c4];
    }
    for (int i = tid; i < 64 * 16; i += 256) {
      int r = i >> 4;
      int kc = (i & 15) << 2;
      int gr = rowBase + r;
      float4 v = make_float4(0.f, 0.f, 0.f, 0.f);
      if (gr < NN) v = *(const float4*)(X + (size_t)gr * CIN + kb + kc);
      Xs[(kc + 0) * 65 + r] = v.x;
      Xs[(kc + 1) * 65 + r] = v.y;
      Xs[(kc + 2) * 65 + r] = v.z;
      Xs[(kc + 3) * 65 + r] = v.w;
    }
    __syncthreads();
#pragma unroll 4
    for (int k = 0; k < 64; k++) {
      float xv[4];
#pragma unroll
      for (int i = 0; i < 4; i++) xv[i] = Xs[k * 65 + r0 + i];
      float4 w0 = *(const float4*)&Ws[k * CHID + c0];
      float4 w1 = *(const float4*)&Ws[k * CHID + c0 + 4];
      float wv[8] = {w0.x, w0.y, w0.z, w0.w, w1.x, w1.y, w1.z, w1.w};
#pragma unroll
      for (int i = 0; i < 4; i++)
#pragma unroll
        for (int j = 0; j < 8; j++) acc[i][j] = fmaf(xv[i], wv[j], acc[i][j]);
    }
  }

#pragma unroll
  for (int i = 0; i < 4; i++) {
    int gr = rowBase + r0 + i;
    if (gr < NN) {
      float dn = dinv[gr];
      __half2 h4[4];
#pragma unroll
      for (int j = 0; j < 4; j++)
        h4[j] = __half2(__float2half(dn * acc[i][2 * j]),
                        __float2half(dn * acc[i][2 * j + 1]));
      *(float4*)(G + (size_t)gr * CHID + c0) = *(float4*)h4;
    }
  }
}

// ---------------- GEMM 2: G2[N,64] = fp16(dinv * (O1 @ W2)) ----------------
// 128 rows/block, 256 threads, thread tile 4x8, K chunked by 64.
__global__ __launch_bounds__(256) void k_gemm2(const float* __restrict__ X,
                                               const float* __restrict__ W,
                                               const float* __restrict__ dinv,
                                               __half* __restrict__ G) {
  __shared__ float Ws[64 * COUT];    // 16 KB
  __shared__ float Xs[64 * 129];     // 33 KB
  int tid = threadIdx.x;
  int rowBase = blockIdx.x * 128;
  int tx = tid & 7, ty = tid >> 3;
  int c0 = tx * 8, r0 = ty * 4;

  float acc[4][8];
#pragma unroll
  for (int i = 0; i < 4; i++)
#pragma unroll
    for (int j = 0; j < 8; j++) acc[i][j] = 0.f;

  for (int kb = 0; kb < CHID; kb += 64) {
    __syncthreads();
    for (int i = tid; i < 64 * 16; i += 256) {
      int r = i >> 4, c4 = i & 15;
      ((float4*)Ws)[i] = ((const float4*)W)[(size_t)(kb + r) * 16 + c4];
    }
    for (int i = tid; i < 128 * 16; i += 256) {
      int r = i >> 4;
      int kc = (i & 15) << 2;
      int gr = rowBase + r;
      float4 v = make_float4(0.f, 0.f, 0.f, 0.f);
      if (gr < NN) v = *(const float4*)(X + (size_t)gr * CHID + kb + kc);
      Xs[(kc + 0) * 129 + r] = v.x;
      Xs[(kc + 1) * 129 + r] = v.y;
      Xs[(kc + 2) * 129 + r] = v.z;
      Xs[(kc + 3) * 129 + r] = v.w;
    }
    __syncthreads();
#pragma unroll 4
    for (int k = 0; k < 64; k++) {
      float xv[4];
#pragma unroll
      for (int i = 0; i < 4; i++) xv[i] = Xs[k * 129 + r0 + i];
      float4 w0 = *(const float4*)&Ws[k * COUT + c0];
      float4 w1 = *(const float4*)&Ws[k * COUT + c0 + 4];
      float wv[8] = {w0.x, w0.y, w0.z, w0.w, w1.x, w1.y, w1.z, w1.w};
#pragma unroll
      for (int i = 0; i < 4; i++)
#pragma unroll
        for (int j = 0; j < 8; j++) acc[i][j] = fmaf(xv[i], wv[j], acc[i][j]);
    }
  }

#pragma unroll
  for (int i = 0; i < 4; i++) {
    int gr = rowBase + r0 + i;
    if (gr < NN) {
      float dn = dinv[gr];
      __half2 h4[4];
#pragma unroll
      for (int j = 0; j < 4; j++)
        h4[j] = __half2(__float2half(dn * acc[i][2 * j]),
                        __float2half(dn * acc[i][2 * j + 1]));
      *(float4*)(G + (size_t)gr * COUT + c0) = *(float4*)h4;
    }
  }
}

// ---------------- aggregation (pull, one wave per node) ----------------
// layer 1: o1 = relu(dn * (sum_e g[src] + g[wid]) + b), C=128, lane owns 2 ch
__global__ __launch_bounds__(256) void k_agg1(const __half* __restrict__ g,
                                              const int* __restrict__ rs,
                                              const int* __restrict__ csr,
                                              const float* __restrict__ dinv,
                                              const float* __restrict__ b,
                                              float* __restrict__ o) {
  int wid = (blockIdx.x * blockDim.x + threadIdx.x) >> 6;
  int lane = threadIdx.x & 63;
  if (wid >= NN) return;
  const __half2* gp = (const __half2*)g;

  float2 self = __half22float2(gp[(size_t)wid * 64 + lane]);
  float a0x = self.x, a0y = self.y;
  float a1x = 0.f, a1y = 0.f, a2x = 0.f, a2y = 0.f, a3x = 0.f, a3y = 0.f;

  int e0 = rs[wid];
  int deg = rs[wid + 1] - e0;
  for (int base = 0; base < deg; base += 64) {
    int rem = deg - base;
    int m = rem < 64 ? rem : 64;
    int idx = (lane < m) ? csr[e0 + base + lane] : 0;
    int j = 0;
    for (; j + 3 < m; j += 4) {
      int s0 = __shfl(idx, j);
      int s1 = __shfl(idx, j + 1);
      int s2 = __shfl(idx, j + 2);
      int s3 = __shfl(idx, j + 3);
      float2 v0 = __half22float2(gp[(size_t)s0 * 64 + lane]);
      float2 v1 = __half22float2(gp[(size_t)s1 * 64 + lane]);
      float2 v2 = __half22float2(gp[(size_t)s2 * 64 + lane]);
      float2 v3 = __half22float2(gp[(size_t)s3 * 64 + lane]);
      a0x += v0.x; a0y += v0.y;
      a1x += v1.x; a1y += v1.y;
      a2x += v2.x; a2y += v2.y;
      a3x += v3.x; a3y += v3.y;
    }
    for (; j < m; j++) {
      int s = __shfl(idx, j);
      float2 v = __half22float2(gp[(size_t)s * 64 + lane]);
      a0x += v.x; a0y += v.y;
    }
  }
  float ax = (a0x + a1x) + (a2x + a3x);
  float ay = (a0y + a1y) + (a2y + a3y);
  float dn = dinv[wid];
  float2 bb = ((const float2*)b)[lane];
  ((float2*)o)[(size_t)wid * 64 + lane] =
      make_float2(fmaxf(fmaf(dn, ax, bb.x), 0.f),
                  fmaxf(fmaf(dn, ay, bb.y), 0.f));
}

// layer 2: out = dn * (sum_e g[src] + g[wid]) + b, C=64, lane owns 1 ch
__global__ __launch_bounds__(256) void k_agg2(const __half* __restrict__ g,
                                              const int* __restrict__ rs,
                                              const int* __restrict__ csr,
                                              const float* __restrict__ dinv,
                                              const float* __restrict__ b,
                                              float* __restrict__ o) {
  int wid = (blockIdx.x * blockDim.x + threadIdx.x) >> 6;
  int lane = threadIdx.x & 63;
  if (wid >= NN) return;

  float a0 = __half2float(g[(size_t)wid * COUT + lane]);
  float a1 = 0.f, a2 = 0.f, a3 = 0.f;

  int e0 = rs[wid];
  int deg = rs[wid + 1] - e0;
  for (int base = 0; base < deg; base += 64) {
    int rem = deg - base;
    int m = rem < 64 ? rem : 64;
    int idx = (lane < m) ? csr[e0 + base + lane] : 0;
    int j = 0;
    for (; j + 3 < m; j += 4) {
      int s0 = __shfl(idx, j);
      int s1 = __shfl(idx, j + 1);
      int s2 = __shfl(idx, j + 2);
      int s3 = __shfl(idx, j + 3);
      a0 += __half2float(g[(size_t)s0 * COUT + lane]);
      a1 += __half2float(g[(size_t)s1 * COUT + lane]);
      a2 += __half2float(g[(size_t)s2 * COUT + lane]);
      a3 += __half2float(g[(size_t)s3 * COUT + lane]);
    }
    for (; j < m; j++) {
      int s = __shfl(idx, j);
      a0 += __half2float(g[(size_t)s * COUT + lane]);
    }
  }
  float acc = (a0 + a1) + (a2 + a3);
  o[(size_t)wid * COUT + lane] = fmaf(dinv[wid], acc, b[lane]);
}

// ---------------- launch ----------------

extern "C" void kernel_launch(void* const* d_in, const int* in_sizes, int n_in,
                              void* d_out, int out_size, void* d_ws, size_t ws_size,
                              hipStream_t stream) {
  const float* x  = (const float*)d_in[0];
  const int*   ei = (const int*)d_in[1];
  const float* W1 = (const float*)d_in[2];
  const float* b1 = (const float*)d_in[3];
  const float* W2 = (const float*)d_in[4];
  const float* b2 = (const float*)d_in[5];
  float* out = (float*)d_out;

  const int* esrc = ei;
  const int* edst = ei + NE;

  char* p = (char*)d_ws;
  __half* g1 = (__half*)p;    p += (size_t)NN * CHID * 2;   // 25.6 MB
  float* o1 = (float*)p;      p += (size_t)NN * CHID * 4;   // 51.2 MB
  __half* g2 = (__half*)p;    p += (size_t)NN * COUT * 2;   // 12.8 MB
  int* cnt = (int*)p;         p += (size_t)NN * 4;
  int* rs  = (int*)p;         p += (size_t)(NN + 1) * 4;
  int* cursor = (int*)p;      p += (size_t)NN * 4;
  float* dinv = (float*)p;    p += (size_t)NN * 4;
  int* bs  = (int*)p;         p += (size_t)256 * 4;
  int* csr = (int*)p;         p += (size_t)NE * 4;          // 6.4 MB

  // preprocessing: degrees, dinv, CSR by dst
  hipLaunchKernelGGL(k_zero, dim3((NN + 255) / 256), dim3(256), 0, stream, cnt, NN);
  hipLaunchKernelGGL(k_count, dim3((NE + 255) / 256), dim3(256), 0, stream, edst, cnt);
  hipLaunchKernelGGL(k_scan_a, dim3(NBLK_A), dim3(SCAN_B), 0, stream, cnt, rs, bs);
  hipLaunchKernelGGL(k_scan_b, dim3(1), dim3(256), 0, stream, bs);
  hipLaunchKernelGGL(k_scan_c, dim3(NBLK_A), dim3(SCAN_B), 0, stream, rs, bs, cursor, cnt, dinv);
  hipLaunchKernelGGL(k_fill, dim3((NE + 255) / 256), dim3(256), 0, stream, esrc, edst, cursor, csr);

  // layer 1
  hipLaunchKernelGGL(k_gemm1, dim3((NN + 63) / 64), dim3(256), 0, stream, x, W1, dinv, g1);
  hipLaunchKernelGGL(k_agg1, dim3((NN + 3) / 4), dim3(256), 0, stream, g1, rs, csr, dinv, b1, o1);

  // layer 2
  hipLaunchKernelGGL(k_gemm2, dim3((NN + 127) / 128), dim3(256), 0, stream, o1, W2, dinv, g2);
  hipLaunchKernelGGL(k_agg2, dim3((NN + 3) / 4), dim3(256), 0, stream, g2, rs, csr, dinv, b2, out);
}

// Round 3
// 271.831 us; speedup vs baseline: 2.2618x; 1.5478x over previous
//
#include <hip/hip_runtime.h>
#include <hip/hip_fp16.h>

#define NN   100000
#define NE   1600000
#define CIN  128
#define CHID 128
#define COUT 64

// two-level CSR build
#define NPB  256                  // nodes per bucket (dst >> 8)
#define NB   391                  // ceil(NN / NPB)
#define NBLK 128                  // partition blocks
#define CHUNK ((NE + NBLK - 1) / NBLK)   // 12500

// ---------------- pass A: per-(bucket,block) histogram ----------------
__global__ __launch_bounds__(512) void k_passA(const int* __restrict__ dst,
                                               int* __restrict__ tab) {
  __shared__ int hist[NB];
  int tid = threadIdx.x;
  for (int t = tid; t < NB; t += 512) hist[t] = 0;
  __syncthreads();
  int i0 = blockIdx.x * CHUNK;
  int i1 = min(i0 + CHUNK, NE);
  for (int i = i0 + tid; i < i1; i += 512)
    atomicAdd(&hist[((unsigned)dst[i]) >> 8], 1);
  __syncthreads();
  for (int t = tid; t < NB; t += 512)
    tab[t * NBLK + blockIdx.x] = hist[t];
}

// ---------------- bucket-total exclusive scan ----------------
__global__ __launch_bounds__(512) void k_bscan(const int* __restrict__ tab,
                                               int* __restrict__ bb) {
  __shared__ int s[512];
  int t = threadIdx.x;
  int v = 0;
  if (t < NB) {
    const int* row = tab + t * NBLK;
#pragma unroll 8
    for (int k = 0; k < NBLK; k++) v += row[k];
  }
  s[t] = v;
  __syncthreads();
  for (int off = 1; off < 512; off <<= 1) {
    int u = (t >= off) ? s[t - off] : 0;
    __syncthreads();
    s[t] += u;
    __syncthreads();
  }
  if (t < NB) bb[t] = s[t] - v;
  if (t == 0) bb[NB] = NE;
}

// ---------------- per-bucket block-offset scan ----------------
__global__ __launch_bounds__(128) void k_tabscan(int* __restrict__ tab,
                                                 const int* __restrict__ bb) {
  __shared__ int s[128];
  int b = blockIdx.x, t = threadIdx.x;
  int v = tab[b * NBLK + t];
  s[t] = v;
  __syncthreads();
  for (int off = 1; off < 128; off <<= 1) {
    int u = (t >= off) ? s[t - off] : 0;
    __syncthreads();
    s[t] += u;
    __syncthreads();
  }
  tab[b * NBLK + t] = bb[b] + s[t] - v;
}

// ---------------- pass B: scatter edges into bucket array ----------------
// entry = (src << 8) | (dst & 255);  src < 2^17 so this fits 25 bits
__global__ __launch_bounds__(512) void k_passB(const int* __restrict__ src,
                                               const int* __restrict__ dst,
                                               const int* __restrict__ tab,
                                               int* __restrict__ barr) {
  __shared__ int cur[NB];
  int tid = threadIdx.x;
  for (int t = tid; t < NB; t += 512) cur[t] = tab[t * NBLK + blockIdx.x];
  __syncthreads();
  int i0 = blockIdx.x * CHUNK;
  int i1 = min(i0 + CHUNK, NE);
  for (int i = i0 + tid; i < i1; i += 512) {
    int d = dst[i];
    unsigned b = ((unsigned)d) >> 8;
    int p = atomicAdd(&cur[b], 1);
    barr[p] = (src[i] << 8) | (d & 255);
  }
}

// ---------------- level 2: per-bucket count/scan/scatter → csr, rs, dinv ----
__global__ __launch_bounds__(256) void k_l2(const int* __restrict__ barr,
                                            const int* __restrict__ bb,
                                            int* __restrict__ csr,
                                            int* __restrict__ rs,
                                            float* __restrict__ dinv) {
  __shared__ int lcnt[NPB];
  __shared__ int lcur[NPB];
  int b = blockIdx.x, t = threadIdx.x;
  int e0 = bb[b], e1 = bb[b + 1];
  lcnt[t] = 0;
  __syncthreads();
  for (int i = e0 + t; i < e1; i += 256) atomicAdd(&lcnt[barr[i] & 255], 1);
  __syncthreads();
  int v = lcnt[t];
  lcur[t] = v;
  __syncthreads();
  for (int off = 1; off < 256; off <<= 1) {
    int u = (t >= off) ? lcur[t - off] : 0;
    __syncthreads();
    lcur[t] += u;
    __syncthreads();
  }
  int ex = lcur[t] - v;
  __syncthreads();
  lcur[t] = e0 + ex;
  int g = b * NPB + t;
  if (g <= NN) rs[g] = e0 + ex;
  if (g < NN) dinv[g] = rsqrtf((float)v + 1.0f);
  __syncthreads();
  for (int i = e0 + t; i < e1; i += 256) {
    int w = barr[i];
    int p = atomicAdd(&lcur[w & 255], 1);
    csr[p] = ((unsigned)w) >> 8;
  }
}

// ---------------- GEMM 1: G1[N,128] = fp16(dinv * (X @ W1)) ----------------
__global__ __launch_bounds__(256) void k_gemm1(const float* __restrict__ X,
                                               const float* __restrict__ W,
                                               const float* __restrict__ dinv,
                                               __half* __restrict__ G) {
  __shared__ float Ws[64 * CHID];   // 32 KB
  __shared__ float Xs[64 * 65];     // 16.6 KB, transposed [k][r]
  int tid = threadIdx.x;
  int rowBase = blockIdx.x * 64;
  int tx = tid & 15, ty = tid >> 4;
  int c0 = tx * 8, r0 = ty * 4;

  float acc[4][8];
#pragma unroll
  for (int i = 0; i < 4; i++)
#pragma unroll
    for (int j = 0; j < 8; j++) acc[i][j] = 0.f;

  for (int kb = 0; kb < CIN; kb += 64) {
    __syncthreads();
    for (int i = tid; i < 64 * 32; i += 256) {
      int r = i >> 5, c4 = i & 31;
      ((float4*)Ws)[i] = ((const float4*)W)[(size_t)(kb + r) * 32 + c4];
    }
    for (int i = tid; i < 64 * 16; i += 256) {
      int r = i >> 4;
      int kc = (i & 15) << 2;
      int gr = rowBase + r;
      float4 v = make_float4(0.f, 0.f, 0.f, 0.f);
      if (gr < NN) v = *(const float4*)(X + (size_t)gr * CIN + kb + kc);
      Xs[(kc + 0) * 65 + r] = v.x;
      Xs[(kc + 1) * 65 + r] = v.y;
      Xs[(kc + 2) * 65 + r] = v.z;
      Xs[(kc + 3) * 65 + r] = v.w;
    }
    __syncthreads();
#pragma unroll 4
    for (int k = 0; k < 64; k++) {
      float xv[4];
#pragma unroll
      for (int i = 0; i < 4; i++) xv[i] = Xs[k * 65 + r0 + i];
      float4 w0 = *(const float4*)&Ws[k * CHID + c0];
      float4 w1 = *(const float4*)&Ws[k * CHID + c0 + 4];
      float wv[8] = {w0.x, w0.y, w0.z, w0.w, w1.x, w1.y, w1.z, w1.w};
#pragma unroll
      for (int i = 0; i < 4; i++)
#pragma unroll
        for (int j = 0; j < 8; j++) acc[i][j] = fmaf(xv[i], wv[j], acc[i][j]);
    }
  }

#pragma unroll
  for (int i = 0; i < 4; i++) {
    int gr = rowBase + r0 + i;
    if (gr < NN) {
      float dn = dinv[gr];
      __half2 h4[4];
#pragma unroll
      for (int j = 0; j < 4; j++)
        h4[j] = __half2(__float2half(dn * acc[i][2 * j]),
                        __float2half(dn * acc[i][2 * j + 1]));
      *(float4*)(G + (size_t)gr * CHID + c0) = *(float4*)h4;
    }
  }
}

// ---------------- GEMM 2: G2[N,64] = fp16(dinv * (O1 @ W2)) ----------------
__global__ __launch_bounds__(256) void k_gemm2(const float* __restrict__ X,
                                               const float* __restrict__ W,
                                               const float* __restrict__ dinv,
                                               __half* __restrict__ G) {
  __shared__ float Ws[64 * COUT];    // 16 KB
  __shared__ float Xs[64 * 129];     // 33 KB
  int tid = threadIdx.x;
  int rowBase = blockIdx.x * 128;
  int tx = tid & 7, ty = tid >> 3;
  int c0 = tx * 8, r0 = ty * 4;

  float acc[4][8];
#pragma unroll
  for (int i = 0; i < 4; i++)
#pragma unroll
    for (int j = 0; j < 8; j++) acc[i][j] = 0.f;

  for (int kb = 0; kb < CHID; kb += 64) {
    __syncthreads();
    for (int i = tid; i < 64 * 16; i += 256) {
      int r = i >> 4, c4 = i & 15;
      ((float4*)Ws)[i] = ((const float4*)W)[(size_t)(kb + r) * 16 + c4];
    }
    for (int i = tid; i < 128 * 16; i += 256) {
      int r = i >> 4;
      int kc = (i & 15) << 2;
      int gr = rowBase + r;
      float4 v = make_float4(0.f, 0.f, 0.f, 0.f);
      if (gr < NN) v = *(const float4*)(X + (size_t)gr * CHID + kb + kc);
      Xs[(kc + 0) * 129 + r] = v.x;
      Xs[(kc + 1) * 129 + r] = v.y;
      Xs[(kc + 2) * 129 + r] = v.z;
      Xs[(kc + 3) * 129 + r] = v.w;
    }
    __syncthreads();
#pragma unroll 4
    for (int k = 0; k < 64; k++) {
      float xv[4];
#pragma unroll
      for (int i = 0; i < 4; i++) xv[i] = Xs[k * 129 + r0 + i];
      float4 w0 = *(const float4*)&Ws[k * COUT + c0];
      float4 w1 = *(const float4*)&Ws[k * COUT + c0 + 4];
      float wv[8] = {w0.x, w0.y, w0.z, w0.w, w1.x, w1.y, w1.z, w1.w};
#pragma unroll
      for (int i = 0; i < 4; i++)
#pragma unroll
        for (int j = 0; j < 8; j++) acc[i][j] = fmaf(xv[i], wv[j], acc[i][j]);
    }
  }

#pragma unroll
  for (int i = 0; i < 4; i++) {
    int gr = rowBase + r0 + i;
    if (gr < NN) {
      float dn = dinv[gr];
      __half2 h4[4];
#pragma unroll
      for (int j = 0; j < 4; j++)
        h4[j] = __half2(__float2half(dn * acc[i][2 * j]),
                        __float2half(dn * acc[i][2 * j + 1]));
      *(float4*)(G + (size_t)gr * COUT + c0) = *(float4*)h4;
    }
  }
}

// ---------------- aggregation (pull, one wave per node) ----------------
// layer 1: o1 = relu(dn * (sum_e g[src] + g[wid]) + b), C=128, lane owns 2 ch
__global__ __launch_bounds__(256) void k_agg1(const __half* __restrict__ g,
                                              const int* __restrict__ rs,
                                              const int* __restrict__ csr,
                                              const float* __restrict__ dinv,
                                              const float* __restrict__ b,
                                              float* __restrict__ o) {
  int wid = (blockIdx.x * blockDim.x + threadIdx.x) >> 6;
  int lane = threadIdx.x & 63;
  if (wid >= NN) return;
  const __half2* gp = (const __half2*)g;

  float2 self = __half22float2(gp[(size_t)wid * 64 + lane]);
  float a0x = self.x, a0y = self.y;
  float a1x = 0.f, a1y = 0.f, a2x = 0.f, a2y = 0.f, a3x = 0.f, a3y = 0.f;

  int e0 = rs[wid];
  int deg = rs[wid + 1] - e0;
  for (int base = 0; base < deg; base += 64) {
    int rem = deg - base;
    int m = rem < 64 ? rem : 64;
    int idx = (lane < m) ? csr[e0 + base + lane] : 0;
    int j = 0;
    for (; j + 3 < m; j += 4) {
      int s0 = __shfl(idx, j);
      int s1 = __shfl(idx, j + 1);
      int s2 = __shfl(idx, j + 2);
      int s3 = __shfl(idx, j + 3);
      float2 v0 = __half22float2(gp[(size_t)s0 * 64 + lane]);
      float2 v1 = __half22float2(gp[(size_t)s1 * 64 + lane]);
      float2 v2 = __half22float2(gp[(size_t)s2 * 64 + lane]);
      float2 v3 = __half22float2(gp[(size_t)s3 * 64 + lane]);
      a0x += v0.x; a0y += v0.y;
      a1x += v1.x; a1y += v1.y;
      a2x += v2.x; a2y += v2.y;
      a3x += v3.x; a3y += v3.y;
    }
    for (; j < m; j++) {
      int s = __shfl(idx, j);
      float2 v = __half22float2(gp[(size_t)s * 64 + lane]);
      a0x += v.x; a0y += v.y;
    }
  }
  float ax = (a0x + a1x) + (a2x + a3x);
  float ay = (a0y + a1y) + (a2y + a3y);
  float dn = dinv[wid];
  float2 bb = ((const float2*)b)[lane];
  ((float2*)o)[(size_t)wid * 64 + lane] =
      make_float2(fmaxf(fmaf(dn, ax, bb.x), 0.f),
                  fmaxf(fmaf(dn, ay, bb.y), 0.f));
}

// layer 2: out = dn * (sum_e g[src] + g[wid]) + b, C=64, lane owns 1 ch
__global__ __launch_bounds__(256) void k_agg2(const __half* __restrict__ g,
                                              const int* __restrict__ rs,
                                              const int* __restrict__ csr,
                                              const float* __restrict__ dinv,
                                              const float* __restrict__ b,
                                              float* __restrict__ o) {
  int wid = (blockIdx.x * blockDim.x + threadIdx.x) >> 6;
  int lane = threadIdx.x & 63;
  if (wid >= NN) return;

  float a0 = __half2float(g[(size_t)wid * COUT + lane]);
  float a1 = 0.f, a2 = 0.f, a3 = 0.f;

  int e0 = rs[wid];
  int deg = rs[wid + 1] - e0;
  for (int base = 0; base < deg; base += 64) {
    int rem = deg - base;
    int m = rem < 64 ? rem : 64;
    int idx = (lane < m) ? csr[e0 + base + lane] : 0;
    int j = 0;
    for (; j + 3 < m; j += 4) {
      int s0 = __shfl(idx, j);
      int s1 = __shfl(idx, j + 1);
      int s2 = __shfl(idx, j + 2);
      int s3 = __shfl(idx, j + 3);
      a0 += __half2float(g[(size_t)s0 * COUT + lane]);
      a1 += __half2float(g[(size_t)s1 * COUT + lane]);
      a2 += __half2float(g[(size_t)s2 * COUT + lane]);
      a3 += __half2float(g[(size_t)s3 * COUT + lane]);
    }
    for (; j < m; j++) {
      int s = __shfl(idx, j);
      a0 += __half2float(g[(size_t)s * COUT + lane]);
    }
  }
  float acc = (a0 + a1) + (a2 + a3);
  o[(size_t)wid * COUT + lane] = fmaf(dinv[wid], acc, b[lane]);
}

// ---------------- launch ----------------

extern "C" void kernel_launch(void* const* d_in, const int* in_sizes, int n_in,
                              void* d_out, int out_size, void* d_ws, size_t ws_size,
                              hipStream_t stream) {
  const float* x  = (const float*)d_in[0];
  const int*   ei = (const int*)d_in[1];
  const float* W1 = (const float*)d_in[2];
  const float* b1 = (const float*)d_in[3];
  const float* W2 = (const float*)d_in[4];
  const float* b2 = (const float*)d_in[5];
  float* out = (float*)d_out;

  const int* esrc = ei;
  const int* edst = ei + NE;

  char* p = (char*)d_ws;
  __half* g1 = (__half*)p;    p += (size_t)NN * CHID * 2;   // 25.6 MB
  float* o1 = (float*)p;      p += (size_t)NN * CHID * 4;   // 51.2 MB
  __half* g2 = (__half*)p;    p += (size_t)NN * COUT * 2;   // 12.8 MB
  int* rs  = (int*)p;         p += (size_t)(NN + 1) * 4;
  float* dinv = (float*)p;    p += (size_t)NN * 4;
  int* tab = (int*)p;         p += (size_t)NB * NBLK * 4;   // 200 KB
  int* bb  = (int*)p;         p += (size_t)(NB + 1) * 4;
  int* barr = (int*)p;        p += (size_t)NE * 4;          // 6.4 MB
  int* csr = (int*)p;         p += (size_t)NE * 4;          // 6.4 MB

  // CSR build (two-level partition, write-combine friendly)
  hipLaunchKernelGGL(k_passA, dim3(NBLK), dim3(512), 0, stream, edst, tab);
  hipLaunchKernelGGL(k_bscan, dim3(1), dim3(512), 0, stream, tab, bb);
  hipLaunchKernelGGL(k_tabscan, dim3(NB), dim3(128), 0, stream, tab, bb);
  hipLaunchKernelGGL(k_passB, dim3(NBLK), dim3(512), 0, stream, esrc, edst, tab, barr);
  hipLaunchKernelGGL(k_l2, dim3(NB), dim3(256), 0, stream, barr, bb, csr, rs, dinv);

  // layer 1
  hipLaunchKernelGGL(k_gemm1, dim3((NN + 63) / 64), dim3(256), 0, stream, x, W1, dinv, g1);
  hipLaunchKernelGGL(k_agg1, dim3((NN + 3) / 4), dim3(256), 0, stream, g1, rs, csr, dinv, b1, o1);

  // layer 2
  hipLaunchKernelGGL(k_gemm2, dim3((NN + 127) / 128), dim3(256), 0, stream, o1, W2, dinv, g2);
  hipLaunchKernelGGL(k_agg2, dim3((NN + 3) / 4), dim3(256), 0, stream, g2, rs, csr, dinv, b2, out);
}

// Round 4
// 219.919 us; speedup vs baseline: 2.7957x; 1.2360x over previous
//
#include <hip/hip_runtime.h>
#include <hip/hip_fp16.h>

#define NN   100000
#define NE   1600000
#define CIN  128
#define CHID 128
#define COUT 64

// two-level CSR build
#define NPB  256                  // nodes per bucket (dst >> 8)
#define NB   391                  // ceil(NN / NPB)
#define NBLK 128                  // partition blocks
#define CHUNK ((NE + NBLK - 1) / NBLK)   // 12500

// MFMA types
typedef _Float16 f16x8 __attribute__((ext_vector_type(8)));
typedef float    f32x4 __attribute__((ext_vector_type(4)));

#define NTILE 782   // ceil(NN/128)
#define GGRID 512

// ---------------- pass A: per-(bucket,block) histogram ----------------
__global__ __launch_bounds__(512) void k_passA(const int* __restrict__ dst,
                                               int* __restrict__ tab) {
  __shared__ int hist[NB];
  int tid = threadIdx.x;
  for (int t = tid; t < NB; t += 512) hist[t] = 0;
  __syncthreads();
  int i0 = blockIdx.x * CHUNK;
  int i1 = min(i0 + CHUNK, NE);
  for (int i = i0 + tid; i < i1; i += 512)
    atomicAdd(&hist[((unsigned)dst[i]) >> 8], 1);
  __syncthreads();
  for (int t = tid; t < NB; t += 512)
    tab[t * NBLK + blockIdx.x] = hist[t];
}

// ---------------- bucket-total exclusive scan ----------------
__global__ __launch_bounds__(512) void k_bscan(const int* __restrict__ tab,
                                               int* __restrict__ bb) {
  __shared__ int s[512];
  int t = threadIdx.x;
  int v = 0;
  if (t < NB) {
    const int* row = tab + t * NBLK;
#pragma unroll 8
    for (int k = 0; k < NBLK; k++) v += row[k];
  }
  s[t] = v;
  __syncthreads();
  for (int off = 1; off < 512; off <<= 1) {
    int u = (t >= off) ? s[t - off] : 0;
    __syncthreads();
    s[t] += u;
    __syncthreads();
  }
  if (t < NB) bb[t] = s[t] - v;
  if (t == 0) bb[NB] = NE;
}

// ---------------- per-bucket block-offset scan ----------------
__global__ __launch_bounds__(128) void k_tabscan(int* __restrict__ tab,
                                                 const int* __restrict__ bb) {
  __shared__ int s[128];
  int b = blockIdx.x, t = threadIdx.x;
  int v = tab[b * NBLK + t];
  s[t] = v;
  __syncthreads();
  for (int off = 1; off < 128; off <<= 1) {
    int u = (t >= off) ? s[t - off] : 0;
    __syncthreads();
    s[t] += u;
    __syncthreads();
  }
  tab[b * NBLK + t] = bb[b] + s[t] - v;
}

// ---------------- pass B: scatter edges into bucket array ----------------
// entry = (src << 8) | (dst & 255);  src < 2^17 so this fits 25 bits
__global__ __launch_bounds__(512) void k_passB(const int* __restrict__ src,
                                               const int* __restrict__ dst,
                                               const int* __restrict__ tab,
                                               int* __restrict__ barr) {
  __shared__ int cur[NB];
  int tid = threadIdx.x;
  for (int t = tid; t < NB; t += 512) cur[t] = tab[t * NBLK + blockIdx.x];
  __syncthreads();
  int i0 = blockIdx.x * CHUNK;
  int i1 = min(i0 + CHUNK, NE);
  for (int i = i0 + tid; i < i1; i += 512) {
    int d = dst[i];
    unsigned b = ((unsigned)d) >> 8;
    int p = atomicAdd(&cur[b], 1);
    barr[p] = (src[i] << 8) | (d & 255);
  }
}

// ---------------- level 2: per-bucket count/scan/scatter → csr, rs, dinv ----
__global__ __launch_bounds__(256) void k_l2(const int* __restrict__ barr,
                                            const int* __restrict__ bb,
                                            int* __restrict__ csr,
                                            int* __restrict__ rs,
                                            float* __restrict__ dinv) {
  __shared__ int lcnt[NPB];
  __shared__ int lcur[NPB];
  int b = blockIdx.x, t = threadIdx.x;
  int e0 = bb[b], e1 = bb[b + 1];
  lcnt[t] = 0;
  __syncthreads();
  for (int i = e0 + t; i < e1; i += 256) atomicAdd(&lcnt[barr[i] & 255], 1);
  __syncthreads();
  int v = lcnt[t];
  lcur[t] = v;
  __syncthreads();
  for (int off = 1; off < 256; off <<= 1) {
    int u = (t >= off) ? lcur[t - off] : 0;
    __syncthreads();
    lcur[t] += u;
    __syncthreads();
  }
  int ex = lcur[t] - v;
  __syncthreads();
  lcur[t] = e0 + ex;
  int g = b * NPB + t;
  if (g <= NN) rs[g] = e0 + ex;
  if (g < NN) dinv[g] = rsqrtf((float)v + 1.0f);
  __syncthreads();
  for (int i = e0 + t; i < e1; i += 256) {
    int w = barr[i];
    int p = atomicAdd(&lcur[w & 255], 1);
    csr[p] = ((unsigned)w) >> 8;
  }
}

// ---------------- GEMM 1 (MFMA f16): G1[N,128] = f16(dinv*(X @ W1)) --------
// Persistent 512 blocks, 4 waves, wave tile = 32 rows x 128 cols.
// W held in registers as 32 A-frags; X frags loaded direct from global (fp32->f16).
// Swapped operands: D = mfma(Wfrag, Xfrag) -> lane holds row=base+(l&15),
// cols cf*16 + (l>>4)*4 + reg  (C/D layout col=lane&15,row=(lane>>4)*4+reg).
__global__ __launch_bounds__(256, 2) void k_gemm1(const float* __restrict__ X,
                                                  const float* __restrict__ W,
                                                  const float* __restrict__ dinv,
                                                  __half* __restrict__ G) {
  __shared__ _Float16 Wt[128][128];   // [col][k], 32 KB
  int tid = threadIdx.x;
  // one-time: stage W transposed to f16
  for (int i = tid; i < 128 * 32; i += 256) {
    int k = i >> 5, c4 = (i & 31) << 2;
    float4 v = ((const float4*)W)[i];
    Wt[c4 + 0][k] = (_Float16)v.x;
    Wt[c4 + 1][k] = (_Float16)v.y;
    Wt[c4 + 2][k] = (_Float16)v.z;
    Wt[c4 + 3][k] = (_Float16)v.w;
  }
  __syncthreads();
  int wv = tid >> 6, lane = tid & 63;
  int l15 = lane & 15, g = lane >> 4;

  // load all W frags into registers: wf[cf][ks], elem j <- Wt[cf*16+l15][ks*32+g*8+j]
  f16x8 wf[8][4];
#pragma unroll
  for (int cf = 0; cf < 8; cf++)
#pragma unroll
    for (int ks = 0; ks < 4; ks++)
      wf[cf][ks] = *(const f16x8*)&Wt[cf * 16 + l15][ks * 32 + g * 8];

  for (int t = blockIdx.x; t < NTILE; t += GGRID) {
    int rowbase = t * 128 + wv * 32;
    f32x4 acc[2][8];
#pragma unroll
    for (int i = 0; i < 2; i++)
#pragma unroll
      for (int j = 0; j < 8; j++) acc[i][j] = (f32x4){0.f, 0.f, 0.f, 0.f};

    int r0 = min(rowbase + l15, NN - 1);
    int r1 = min(rowbase + 16 + l15, NN - 1);
    const float* p0 = X + (size_t)r0 * CIN + g * 8;
    const float* p1 = X + (size_t)r1 * CIN + g * 8;

    // prefetch ks=0
    float4 u0a = *(const float4*)p0, u0b = *(const float4*)(p0 + 4);
    float4 u1a = *(const float4*)p1, u1b = *(const float4*)(p1 + 4);

#pragma unroll
    for (int ks = 0; ks < 4; ks++) {
      f16x8 xa, xb;
      xa[0] = (_Float16)u0a.x; xa[1] = (_Float16)u0a.y;
      xa[2] = (_Float16)u0a.z; xa[3] = (_Float16)u0a.w;
      xa[4] = (_Float16)u0b.x; xa[5] = (_Float16)u0b.y;
      xa[6] = (_Float16)u0b.z; xa[7] = (_Float16)u0b.w;
      xb[0] = (_Float16)u1a.x; xb[1] = (_Float16)u1a.y;
      xb[2] = (_Float16)u1a.z; xb[3] = (_Float16)u1a.w;
      xb[4] = (_Float16)u1b.x; xb[5] = (_Float16)u1b.y;
      xb[6] = (_Float16)u1b.z; xb[7] = (_Float16)u1b.w;
      if (ks < 3) {
        int o = (ks + 1) * 32;
        u0a = *(const float4*)(p0 + o); u0b = *(const float4*)(p0 + o + 4);
        u1a = *(const float4*)(p1 + o); u1b = *(const float4*)(p1 + o + 4);
      }
#pragma unroll
      for (int cf = 0; cf < 8; cf++) {
        acc[0][cf] = __builtin_amdgcn_mfma_f32_16x16x32_f16(wf[cf][ks], xa, acc[0][cf], 0, 0, 0);
        acc[1][cf] = __builtin_amdgcn_mfma_f32_16x16x32_f16(wf[cf][ks], xb, acc[1][cf], 0, 0, 0);
      }
    }

#pragma unroll
    for (int rf = 0; rf < 2; rf++) {
      int row = rowbase + rf * 16 + l15;
      if (row < NN) {
        float dn = dinv[row];
#pragma unroll
        for (int cf = 0; cf < 8; cf++) {
          int col = cf * 16 + g * 4;
          __half2 h0 = __half2(__float2half(dn * acc[rf][cf][0]),
                               __float2half(dn * acc[rf][cf][1]));
          __half2 h1 = __half2(__float2half(dn * acc[rf][cf][2]),
                               __float2half(dn * acc[rf][cf][3]));
          uint2 s;
          s.x = *(unsigned*)&h0;
          s.y = *(unsigned*)&h1;
          *(uint2*)(G + (size_t)row * CHID + col) = s;
        }
      }
    }
  }
}

// ---------------- GEMM 2 (MFMA f16): G2[N,64] = f16(dinv*(O1 @ W2)) --------
// O1 is already f16; frag load is one 16B read.
__global__ __launch_bounds__(256, 2) void k_gemm2(const __half* __restrict__ X,
                                                  const float* __restrict__ W,
                                                  const float* __restrict__ dinv,
                                                  __half* __restrict__ G) {
  __shared__ _Float16 Wt[64][128];    // [col][k], 16 KB
  int tid = threadIdx.x;
  for (int i = tid; i < 128 * 16; i += 256) {
    int k = i >> 4, c4 = (i & 15) << 2;
    float4 v = ((const float4*)W)[i];
    Wt[c4 + 0][k] = (_Float16)v.x;
    Wt[c4 + 1][k] = (_Float16)v.y;
    Wt[c4 + 2][k] = (_Float16)v.z;
    Wt[c4 + 3][k] = (_Float16)v.w;
  }
  __syncthreads();
  int wv = tid >> 6, lane = tid & 63;
  int l15 = lane & 15, g = lane >> 4;

  f16x8 wf[4][4];
#pragma unroll
  for (int cf = 0; cf < 4; cf++)
#pragma unroll
    for (int ks = 0; ks < 4; ks++)
      wf[cf][ks] = *(const f16x8*)&Wt[cf * 16 + l15][ks * 32 + g * 8];

  for (int t = blockIdx.x; t < NTILE; t += GGRID) {
    int rowbase = t * 128 + wv * 32;
    f32x4 acc[2][4];
#pragma unroll
    for (int i = 0; i < 2; i++)
#pragma unroll
      for (int j = 0; j < 4; j++) acc[i][j] = (f32x4){0.f, 0.f, 0.f, 0.f};

    int r0 = min(rowbase + l15, NN - 1);
    int r1 = min(rowbase + 16 + l15, NN - 1);
    const _Float16* p0 = (const _Float16*)X + (size_t)r0 * CHID + g * 8;
    const _Float16* p1 = (const _Float16*)X + (size_t)r1 * CHID + g * 8;

    f16x8 xa = *(const f16x8*)p0;
    f16x8 xb = *(const f16x8*)p1;

#pragma unroll
    for (int ks = 0; ks < 4; ks++) {
      f16x8 ca = xa, cb = xb;
      if (ks < 3) {
        int o = (ks + 1) * 32;
        xa = *(const f16x8*)(p0 + o);
        xb = *(const f16x8*)(p1 + o);
      }
#pragma unroll
      for (int cf = 0; cf < 4; cf++) {
        acc[0][cf] = __builtin_amdgcn_mfma_f32_16x16x32_f16(wf[cf][ks], ca, acc[0][cf], 0, 0, 0);
        acc[1][cf] = __builtin_amdgcn_mfma_f32_16x16x32_f16(wf[cf][ks], cb, acc[1][cf], 0, 0, 0);
      }
    }

#pragma unroll
    for (int rf = 0; rf < 2; rf++) {
      int row = rowbase + rf * 16 + l15;
      if (row < NN) {
        float dn = dinv[row];
#pragma unroll
        for (int cf = 0; cf < 4; cf++) {
          int col = cf * 16 + g * 4;
          __half2 h0 = __half2(__float2half(dn * acc[rf][cf][0]),
                               __float2half(dn * acc[rf][cf][1]));
          __half2 h1 = __half2(__float2half(dn * acc[rf][cf][2]),
                               __float2half(dn * acc[rf][cf][3]));
          uint2 s;
          s.x = *(unsigned*)&h0;
          s.y = *(unsigned*)&h1;
          *(uint2*)(G + (size_t)row * COUT + col) = s;
        }
      }
    }
  }
}

// ---------------- aggregation (pull, one wave per node) ----------------
// layer 1: o1 = f16(relu(dn * (sum_e g[src] + g[wid]) + b)), C=128
__global__ __launch_bounds__(256) void k_agg1(const __half* __restrict__ g,
                                              const int* __restrict__ rs,
                                              const int* __restrict__ csr,
                                              const float* __restrict__ dinv,
                                              const float* __restrict__ b,
                                              __half* __restrict__ o) {
  int wid = (blockIdx.x * blockDim.x + threadIdx.x) >> 6;
  int lane = threadIdx.x & 63;
  if (wid >= NN) return;
  const __half2* gp = (const __half2*)g;

  float2 self = __half22float2(gp[(size_t)wid * 64 + lane]);
  float a0x = self.x, a0y = self.y;
  float a1x = 0.f, a1y = 0.f, a2x = 0.f, a2y = 0.f, a3x = 0.f, a3y = 0.f;

  int e0 = rs[wid];
  int deg = rs[wid + 1] - e0;
  for (int base = 0; base < deg; base += 64) {
    int rem = deg - base;
    int m = rem < 64 ? rem : 64;
    int idx = (lane < m) ? csr[e0 + base + lane] : 0;
    int j = 0;
    for (; j + 3 < m; j += 4) {
      int s0 = __shfl(idx, j);
      int s1 = __shfl(idx, j + 1);
      int s2 = __shfl(idx, j + 2);
      int s3 = __shfl(idx, j + 3);
      float2 v0 = __half22float2(gp[(size_t)s0 * 64 + lane]);
      float2 v1 = __half22float2(gp[(size_t)s1 * 64 + lane]);
      float2 v2 = __half22float2(gp[(size_t)s2 * 64 + lane]);
      float2 v3 = __half22float2(gp[(size_t)s3 * 64 + lane]);
      a0x += v0.x; a0y += v0.y;
      a1x += v1.x; a1y += v1.y;
      a2x += v2.x; a2y += v2.y;
      a3x += v3.x; a3y += v3.y;
    }
    for (; j < m; j++) {
      int s = __shfl(idx, j);
      float2 v = __half22float2(gp[(size_t)s * 64 + lane]);
      a0x += v.x; a0y += v.y;
    }
  }
  float ax = (a0x + a1x) + (a2x + a3x);
  float ay = (a0y + a1y) + (a2y + a3y);
  float dn = dinv[wid];
  float2 bb = ((const float2*)b)[lane];
  float rx = fmaxf(fmaf(dn, ax, bb.x), 0.f);
  float ry = fmaxf(fmaf(dn, ay, bb.y), 0.f);
  ((__half2*)o)[(size_t)wid * 64 + lane] =
      __half2(__float2half(rx), __float2half(ry));
}

// layer 2: out = dn * (sum_e g[src] + g[wid]) + b, C=64, fp32 out
__global__ __launch_bounds__(256) void k_agg2(const __half* __restrict__ g,
                                              const int* __restrict__ rs,
                                              const int* __restrict__ csr,
                                              const float* __restrict__ dinv,
                                              const float* __restrict__ b,
                                              float* __restrict__ o) {
  int wid = (blockIdx.x * blockDim.x + threadIdx.x) >> 6;
  int lane = threadIdx.x & 63;
  if (wid >= NN) return;

  float a0 = __half2float(g[(size_t)wid * COUT + lane]);
  float a1 = 0.f, a2 = 0.f, a3 = 0.f;

  int e0 = rs[wid];
  int deg = rs[wid + 1] - e0;
  for (int base = 0; base < deg; base += 64) {
    int rem = deg - base;
    int m = rem < 64 ? rem : 64;
    int idx = (lane < m) ? csr[e0 + base + lane] : 0;
    int j = 0;
    for (; j + 3 < m; j += 4) {
      int s0 = __shfl(idx, j);
      int s1 = __shfl(idx, j + 1);
      int s2 = __shfl(idx, j + 2);
      int s3 = __shfl(idx, j + 3);
      a0 += __half2float(g[(size_t)s0 * COUT + lane]);
      a1 += __half2float(g[(size_t)s1 * COUT + lane]);
      a2 += __half2float(g[(size_t)s2 * COUT + lane]);
      a3 += __half2float(g[(size_t)s3 * COUT + lane]);
    }
    for (; j < m; j++) {
      int s = __shfl(idx, j);
      a0 += __half2float(g[(size_t)s * COUT + lane]);
    }
  }
  float acc = (a0 + a1) + (a2 + a3);
  o[(size_t)wid * COUT + lane] = fmaf(dinv[wid], acc, b[lane]);
}

// ---------------- launch ----------------

extern "C" void kernel_launch(void* const* d_in, const int* in_sizes, int n_in,
                              void* d_out, int out_size, void* d_ws, size_t ws_size,
                              hipStream_t stream) {
  const float* x  = (const float*)d_in[0];
  const int*   ei = (const int*)d_in[1];
  const float* W1 = (const float*)d_in[2];
  const float* b1 = (const float*)d_in[3];
  const float* W2 = (const float*)d_in[4];
  const float* b2 = (const float*)d_in[5];
  float* out = (float*)d_out;

  const int* esrc = ei;
  const int* edst = ei + NE;

  char* p = (char*)d_ws;
  __half* g1 = (__half*)p;    p += (size_t)NN * CHID * 2;   // 25.6 MB
  __half* o1 = (__half*)p;    p += (size_t)NN * CHID * 2;   // 25.6 MB (f16 now)
  __half* g2 = (__half*)p;    p += (size_t)NN * COUT * 2;   // 12.8 MB
  int* rs  = (int*)p;         p += (size_t)(NN + 1) * 4;
  float* dinv = (float*)p;    p += (size_t)NN * 4;
  int* tab = (int*)p;         p += (size_t)NB * NBLK * 4;   // 200 KB
  int* bb  = (int*)p;         p += (size_t)(NB + 1) * 4;
  int* barr = (int*)p;        p += (size_t)NE * 4;          // 6.4 MB
  int* csr = (int*)p;         p += (size_t)NE * 4;          // 6.4 MB

  // CSR build (two-level partition, write-combine friendly)
  hipLaunchKernelGGL(k_passA, dim3(NBLK), dim3(512), 0, stream, edst, tab);
  hipLaunchKernelGGL(k_bscan, dim3(1), dim3(512), 0, stream, tab, bb);
  hipLaunchKernelGGL(k_tabscan, dim3(NB), dim3(128), 0, stream, tab, bb);
  hipLaunchKernelGGL(k_passB, dim3(NBLK), dim3(512), 0, stream, esrc, edst, tab, barr);
  hipLaunchKernelGGL(k_l2, dim3(NB), dim3(256), 0, stream, barr, bb, csr, rs, dinv);

  // layer 1
  hipLaunchKernelGGL(k_gemm1, dim3(GGRID), dim3(256), 0, stream, x, W1, dinv, g1);
  hipLaunchKernelGGL(k_agg1, dim3((NN + 3) / 4), dim3(256), 0, stream, g1, rs, csr, dinv, b1, o1);

  // layer 2
  hipLaunchKernelGGL(k_gemm2, dim3(GGRID), dim3(256), 0, stream, o1, W2, dinv, g2);
  hipLaunchKernelGGL(k_agg2, dim3((NN + 3) / 4), dim3(256), 0, stream, g2, rs, csr, dinv, b2, out);
}

// Round 5
// 217.410 us; speedup vs baseline: 2.8280x; 1.0115x over previous
//
#include <hip/hip_runtime.h>
#include <hip/hip_fp16.h>

#define NN   100000
#define NE   1600000
#define CIN  128
#define CHID 128
#define COUT 64

// two-level CSR build
#define NPB  256                  // nodes per bucket (dst >> 8)
#define NB   391                  // ceil(NN / NPB)
#define NBLK 128                  // partition blocks
#define CHUNK ((NE + NBLK - 1) / NBLK)   // 12500

// MFMA types
typedef _Float16 f16x8 __attribute__((ext_vector_type(8)));
typedef float    f32x4 __attribute__((ext_vector_type(4)));

#define NTILE 782   // ceil(NN/128)
#define GGRID 512

// ---------------- pass A: per-(bucket,block) histogram ----------------
__global__ __launch_bounds__(512) void k_passA(const int* __restrict__ dst,
                                               int* __restrict__ tab) {
  __shared__ int hist[NB];
  int tid = threadIdx.x;
  for (int t = tid; t < NB; t += 512) hist[t] = 0;
  __syncthreads();
  int i0 = blockIdx.x * CHUNK;
  int i1 = min(i0 + CHUNK, NE);
  for (int i = i0 + tid; i < i1; i += 512)
    atomicAdd(&hist[((unsigned)dst[i]) >> 8], 1);
  __syncthreads();
  for (int t = tid; t < NB; t += 512)
    tab[t * NBLK + blockIdx.x] = hist[t];
}

// ---------------- bucket-total exclusive scan ----------------
__global__ __launch_bounds__(512) void k_bscan(const int* __restrict__ tab,
                                               int* __restrict__ bb) {
  __shared__ int s[512];
  int t = threadIdx.x;
  int v = 0;
  if (t < NB) {
    const int* row = tab + t * NBLK;
#pragma unroll 8
    for (int k = 0; k < NBLK; k++) v += row[k];
  }
  s[t] = v;
  __syncthreads();
  for (int off = 1; off < 512; off <<= 1) {
    int u = (t >= off) ? s[t - off] : 0;
    __syncthreads();
    s[t] += u;
    __syncthreads();
  }
  if (t < NB) bb[t] = s[t] - v;
  if (t == 0) bb[NB] = NE;
}

// ---------------- per-bucket block-offset scan ----------------
__global__ __launch_bounds__(128) void k_tabscan(int* __restrict__ tab,
                                                 const int* __restrict__ bb) {
  __shared__ int s[128];
  int b = blockIdx.x, t = threadIdx.x;
  int v = tab[b * NBLK + t];
  s[t] = v;
  __syncthreads();
  for (int off = 1; off < 128; off <<= 1) {
    int u = (t >= off) ? s[t - off] : 0;
    __syncthreads();
    s[t] += u;
    __syncthreads();
  }
  tab[b * NBLK + t] = bb[b] + s[t] - v;
}

// ---------------- pass B: scatter edges into bucket array ----------------
// entry = (src << 8) | (dst & 255);  src < 2^17 so this fits 25 bits
__global__ __launch_bounds__(512) void k_passB(const int* __restrict__ src,
                                               const int* __restrict__ dst,
                                               const int* __restrict__ tab,
                                               int* __restrict__ barr) {
  __shared__ int cur[NB];
  int tid = threadIdx.x;
  for (int t = tid; t < NB; t += 512) cur[t] = tab[t * NBLK + blockIdx.x];
  __syncthreads();
  int i0 = blockIdx.x * CHUNK;
  int i1 = min(i0 + CHUNK, NE);
  for (int i = i0 + tid; i < i1; i += 512) {
    int d = dst[i];
    unsigned b = ((unsigned)d) >> 8;
    int p = atomicAdd(&cur[b], 1);
    barr[p] = (src[i] << 8) | (d & 255);
  }
}

// ---------------- level 2: per-bucket count/scan/scatter → csr, rs, dinv ----
__global__ __launch_bounds__(256) void k_l2(const int* __restrict__ barr,
                                            const int* __restrict__ bb,
                                            int* __restrict__ csr,
                                            int* __restrict__ rs,
                                            float* __restrict__ dinv) {
  __shared__ int lcnt[NPB];
  __shared__ int lcur[NPB];
  int b = blockIdx.x, t = threadIdx.x;
  int e0 = bb[b], e1 = bb[b + 1];
  lcnt[t] = 0;
  __syncthreads();
  for (int i = e0 + t; i < e1; i += 256) atomicAdd(&lcnt[barr[i] & 255], 1);
  __syncthreads();
  int v = lcnt[t];
  lcur[t] = v;
  __syncthreads();
  for (int off = 1; off < 256; off <<= 1) {
    int u = (t >= off) ? lcur[t - off] : 0;
    __syncthreads();
    lcur[t] += u;
    __syncthreads();
  }
  int ex = lcur[t] - v;
  __syncthreads();
  lcur[t] = e0 + ex;
  int g = b * NPB + t;
  if (g <= NN) rs[g] = e0 + ex;
  if (g < NN) dinv[g] = rsqrtf((float)v + 1.0f);
  __syncthreads();
  for (int i = e0 + t; i < e1; i += 256) {
    int w = barr[i];
    int p = atomicAdd(&lcur[w & 255], 1);
    csr[p] = ((unsigned)w) >> 8;
  }
}

// ---------------- GEMM 1 (MFMA f16): G1[N,128] = f16(dinv*(X @ W1)) --------
__global__ __launch_bounds__(256, 2) void k_gemm1(const float* __restrict__ X,
                                                  const float* __restrict__ W,
                                                  const float* __restrict__ dinv,
                                                  __half* __restrict__ G) {
  __shared__ _Float16 Wt[128][128];   // [col][k], 32 KB
  int tid = threadIdx.x;
  for (int i = tid; i < 128 * 32; i += 256) {
    int k = i >> 5, c4 = (i & 31) << 2;
    float4 v = ((const float4*)W)[i];
    Wt[c4 + 0][k] = (_Float16)v.x;
    Wt[c4 + 1][k] = (_Float16)v.y;
    Wt[c4 + 2][k] = (_Float16)v.z;
    Wt[c4 + 3][k] = (_Float16)v.w;
  }
  __syncthreads();
  int wv = tid >> 6, lane = tid & 63;
  int l15 = lane & 15, g = lane >> 4;

  f16x8 wf[8][4];
#pragma unroll
  for (int cf = 0; cf < 8; cf++)
#pragma unroll
    for (int ks = 0; ks < 4; ks++)
      wf[cf][ks] = *(const f16x8*)&Wt[cf * 16 + l15][ks * 32 + g * 8];

  for (int t = blockIdx.x; t < NTILE; t += GGRID) {
    int rowbase = t * 128 + wv * 32;
    f32x4 acc[2][8];
#pragma unroll
    for (int i = 0; i < 2; i++)
#pragma unroll
      for (int j = 0; j < 8; j++) acc[i][j] = (f32x4){0.f, 0.f, 0.f, 0.f};

    int r0 = min(rowbase + l15, NN - 1);
    int r1 = min(rowbase + 16 + l15, NN - 1);
    const float* p0 = X + (size_t)r0 * CIN + g * 8;
    const float* p1 = X + (size_t)r1 * CIN + g * 8;

    float4 u0a = *(const float4*)p0, u0b = *(const float4*)(p0 + 4);
    float4 u1a = *(const float4*)p1, u1b = *(const float4*)(p1 + 4);

#pragma unroll
    for (int ks = 0; ks < 4; ks++) {
      f16x8 xa, xb;
      xa[0] = (_Float16)u0a.x; xa[1] = (_Float16)u0a.y;
      xa[2] = (_Float16)u0a.z; xa[3] = (_Float16)u0a.w;
      xa[4] = (_Float16)u0b.x; xa[5] = (_Float16)u0b.y;
      xa[6] = (_Float16)u0b.z; xa[7] = (_Float16)u0b.w;
      xb[0] = (_Float16)u1a.x; xb[1] = (_Float16)u1a.y;
      xb[2] = (_Float16)u1a.z; xb[3] = (_Float16)u1a.w;
      xb[4] = (_Float16)u1b.x; xb[5] = (_Float16)u1b.y;
      xb[6] = (_Float16)u1b.z; xb[7] = (_Float16)u1b.w;
      if (ks < 3) {
        int o = (ks + 1) * 32;
        u0a = *(const float4*)(p0 + o); u0b = *(const float4*)(p0 + o + 4);
        u1a = *(const float4*)(p1 + o); u1b = *(const float4*)(p1 + o + 4);
      }
#pragma unroll
      for (int cf = 0; cf < 8; cf++) {
        acc[0][cf] = __builtin_amdgcn_mfma_f32_16x16x32_f16(wf[cf][ks], xa, acc[0][cf], 0, 0, 0);
        acc[1][cf] = __builtin_amdgcn_mfma_f32_16x16x32_f16(wf[cf][ks], xb, acc[1][cf], 0, 0, 0);
      }
    }

#pragma unroll
    for (int rf = 0; rf < 2; rf++) {
      int row = rowbase + rf * 16 + l15;
      if (row < NN) {
        float dn = dinv[row];
#pragma unroll
        for (int cf = 0; cf < 8; cf++) {
          int col = cf * 16 + g * 4;
          __half2 h0 = __half2(__float2half(dn * acc[rf][cf][0]),
                               __float2half(dn * acc[rf][cf][1]));
          __half2 h1 = __half2(__float2half(dn * acc[rf][cf][2]),
                               __float2half(dn * acc[rf][cf][3]));
          uint2 s;
          s.x = *(unsigned*)&h0;
          s.y = *(unsigned*)&h1;
          *(uint2*)(G + (size_t)row * CHID + col) = s;
        }
      }
    }
  }
}

// ---------------- GEMM 2 (MFMA f16): G2[N,64] = f16(dinv*(O1 @ W2)) --------
__global__ __launch_bounds__(256, 2) void k_gemm2(const __half* __restrict__ X,
                                                  const float* __restrict__ W,
                                                  const float* __restrict__ dinv,
                                                  __half* __restrict__ G) {
  __shared__ _Float16 Wt[64][128];    // [col][k], 16 KB
  int tid = threadIdx.x;
  for (int i = tid; i < 128 * 16; i += 256) {
    int k = i >> 4, c4 = (i & 15) << 2;
    float4 v = ((const float4*)W)[i];
    Wt[c4 + 0][k] = (_Float16)v.x;
    Wt[c4 + 1][k] = (_Float16)v.y;
    Wt[c4 + 2][k] = (_Float16)v.z;
    Wt[c4 + 3][k] = (_Float16)v.w;
  }
  __syncthreads();
  int wv = tid >> 6, lane = tid & 63;
  int l15 = lane & 15, g = lane >> 4;

  f16x8 wf[4][4];
#pragma unroll
  for (int cf = 0; cf < 4; cf++)
#pragma unroll
    for (int ks = 0; ks < 4; ks++)
      wf[cf][ks] = *(const f16x8*)&Wt[cf * 16 + l15][ks * 32 + g * 8];

  for (int t = blockIdx.x; t < NTILE; t += GGRID) {
    int rowbase = t * 128 + wv * 32;
    f32x4 acc[2][4];
#pragma unroll
    for (int i = 0; i < 2; i++)
#pragma unroll
      for (int j = 0; j < 4; j++) acc[i][j] = (f32x4){0.f, 0.f, 0.f, 0.f};

    int r0 = min(rowbase + l15, NN - 1);
    int r1 = min(rowbase + 16 + l15, NN - 1);
    const _Float16* p0 = (const _Float16*)X + (size_t)r0 * CHID + g * 8;
    const _Float16* p1 = (const _Float16*)X + (size_t)r1 * CHID + g * 8;

    f16x8 xa = *(const f16x8*)p0;
    f16x8 xb = *(const f16x8*)p1;

#pragma unroll
    for (int ks = 0; ks < 4; ks++) {
      f16x8 ca = xa, cb = xb;
      if (ks < 3) {
        int o = (ks + 1) * 32;
        xa = *(const f16x8*)(p0 + o);
        xb = *(const f16x8*)(p1 + o);
      }
#pragma unroll
      for (int cf = 0; cf < 4; cf++) {
        acc[0][cf] = __builtin_amdgcn_mfma_f32_16x16x32_f16(wf[cf][ks], ca, acc[0][cf], 0, 0, 0);
        acc[1][cf] = __builtin_amdgcn_mfma_f32_16x16x32_f16(wf[cf][ks], cb, acc[1][cf], 0, 0, 0);
      }
    }

#pragma unroll
    for (int rf = 0; rf < 2; rf++) {
      int row = rowbase + rf * 16 + l15;
      if (row < NN) {
        float dn = dinv[row];
#pragma unroll
        for (int cf = 0; cf < 4; cf++) {
          int col = cf * 16 + g * 4;
          __half2 h0 = __half2(__float2half(dn * acc[rf][cf][0]),
                               __float2half(dn * acc[rf][cf][1]));
          __half2 h1 = __half2(__float2half(dn * acc[rf][cf][2]),
                               __float2half(dn * acc[rf][cf][3]));
          uint2 s;
          s.x = *(unsigned*)&h0;
          s.y = *(unsigned*)&h1;
          *(uint2*)(G + (size_t)row * COUT + col) = s;
        }
      }
    }
  }
}

// ---------------- aggregation (pull, one wave per node, paired halves) -----
// layer 1: o1 = f16(relu(dn * (sum_e g[src] + g[wid]) + b)), C=128
// Wave splits into two 32-lane halves; each half gathers a different edge.
// Lane owns 4 channels (8B uint2 loads -> 512 B/instruction/wave).
__global__ __launch_bounds__(256) void k_agg1(const __half* __restrict__ g,
                                              const int* __restrict__ rs,
                                              const int* __restrict__ csr,
                                              const float* __restrict__ dinv,
                                              const float* __restrict__ b,
                                              __half* __restrict__ o) {
  int wid = (blockIdx.x * blockDim.x + threadIdx.x) >> 6;
  int lane = threadIdx.x & 63;
  if (wid >= NN) return;
  int half = lane >> 5, hl = lane & 31;
  const uint2* gp = (const uint2*)g;   // row = 32 uint2 chunks (4 ch each)

  float a0[4] = {0.f, 0.f, 0.f, 0.f};
  float a1[4] = {0.f, 0.f, 0.f, 0.f};
  float a2[4] = {0.f, 0.f, 0.f, 0.f};
  float a3[4] = {0.f, 0.f, 0.f, 0.f};

  if (half == 0) {
    uint2 sv = gp[(size_t)wid * 32 + hl];
    float2 f0 = __half22float2(*(__half2*)&sv.x);
    float2 f1 = __half22float2(*(__half2*)&sv.y);
    a0[0] = f0.x; a0[1] = f0.y; a0[2] = f1.x; a0[3] = f1.y;
  }

#define ACC1(A, V)                                    \
  {                                                   \
    float2 f0 = __half22float2(*(__half2*)&(V).x);    \
    float2 f1 = __half22float2(*(__half2*)&(V).y);    \
    A[0] += f0.x; A[1] += f0.y; A[2] += f1.x; A[3] += f1.y; \
  }

  int e0 = rs[wid];
  int deg = rs[wid + 1] - e0;
  for (int base = 0; base < deg; base += 64) {
    int m = min(deg - base, 64);
    int idx = (lane < m) ? csr[e0 + base + lane] : 0;
    int fp = m >> 1;   // full pairs
    int j = 0;
    for (; j + 3 < fp; j += 4) {
      int s0 = __shfl(idx, 2 * j + half);
      int s1 = __shfl(idx, 2 * (j + 1) + half);
      int s2 = __shfl(idx, 2 * (j + 2) + half);
      int s3 = __shfl(idx, 2 * (j + 3) + half);
      uint2 v0 = gp[(size_t)s0 * 32 + hl];
      uint2 v1 = gp[(size_t)s1 * 32 + hl];
      uint2 v2 = gp[(size_t)s2 * 32 + hl];
      uint2 v3 = gp[(size_t)s3 * 32 + hl];
      ACC1(a0, v0); ACC1(a1, v1); ACC1(a2, v2); ACC1(a3, v3);
    }
    for (; j < fp; j++) {
      int s = __shfl(idx, 2 * j + half);
      uint2 v = gp[(size_t)s * 32 + hl];
      ACC1(a0, v);
    }
    if (m & 1) {
      int s = __shfl(idx, m - 1);
      if (half == 0) {
        uint2 v = gp[(size_t)s * 32 + hl];
        ACC1(a1, v);
      }
    }
  }
#undef ACC1

  float r[4];
#pragma unroll
  for (int c = 0; c < 4; c++) {
    float t = (a0[c] + a1[c]) + (a2[c] + a3[c]);
    r[c] = t + __shfl_xor(t, 32);
  }
  if (half == 0) {
    float dn = dinv[wid];
    float4 bb = *(const float4*)(b + 4 * hl);
    __half2 h0 = __half2(__float2half(fmaxf(fmaf(dn, r[0], bb.x), 0.f)),
                         __float2half(fmaxf(fmaf(dn, r[1], bb.y), 0.f)));
    __half2 h1 = __half2(__float2half(fmaxf(fmaf(dn, r[2], bb.z), 0.f)),
                         __float2half(fmaxf(fmaf(dn, r[3], bb.w), 0.f)));
    uint2 s;
    s.x = *(unsigned*)&h0;
    s.y = *(unsigned*)&h1;
    *(uint2*)(o + (size_t)wid * CHID + 4 * hl) = s;
  }
}

// layer 2: out = dn * (sum_e g[src] + g[wid]) + b, C=64, fp32 out
// Paired halves; lane owns 2 channels (4B __half2 loads -> 256 B/instr/wave).
__global__ __launch_bounds__(256) void k_agg2(const __half* __restrict__ g,
                                              const int* __restrict__ rs,
                                              const int* __restrict__ csr,
                                              const float* __restrict__ dinv,
                                              const float* __restrict__ b,
                                              float* __restrict__ o) {
  int wid = (blockIdx.x * blockDim.x + threadIdx.x) >> 6;
  int lane = threadIdx.x & 63;
  if (wid >= NN) return;
  int half = lane >> 5, hl = lane & 31;
  const __half2* gp = (const __half2*)g;   // row = 32 half2 chunks

  float2 a0 = {0.f, 0.f}, a1 = {0.f, 0.f}, a2 = {0.f, 0.f}, a3 = {0.f, 0.f};

  if (half == 0) {
    float2 f = __half22float2(gp[(size_t)wid * 32 + hl]);
    a0.x = f.x; a0.y = f.y;
  }

  int e0 = rs[wid];
  int deg = rs[wid + 1] - e0;
  for (int base = 0; base < deg; base += 64) {
    int m = min(deg - base, 64);
    int idx = (lane < m) ? csr[e0 + base + lane] : 0;
    int fp = m >> 1;
    int j = 0;
    for (; j + 3 < fp; j += 4) {
      int s0 = __shfl(idx, 2 * j + half);
      int s1 = __shfl(idx, 2 * (j + 1) + half);
      int s2 = __shfl(idx, 2 * (j + 2) + half);
      int s3 = __shfl(idx, 2 * (j + 3) + half);
      float2 v0 = __half22float2(gp[(size_t)s0 * 32 + hl]);
      float2 v1 = __half22float2(gp[(size_t)s1 * 32 + hl]);
      float2 v2 = __half22float2(gp[(size_t)s2 * 32 + hl]);
      float2 v3 = __half22float2(gp[(size_t)s3 * 32 + hl]);
      a0.x += v0.x; a0.y += v0.y;
      a1.x += v1.x; a1.y += v1.y;
      a2.x += v2.x; a2.y += v2.y;
      a3.x += v3.x; a3.y += v3.y;
    }
    for (; j < fp; j++) {
      int s = __shfl(idx, 2 * j + half);
      float2 v = __half22float2(gp[(size_t)s * 32 + hl]);
      a0.x += v.x; a0.y += v.y;
    }
    if (m & 1) {
      int s = __shfl(idx, m - 1);
      if (half == 0) {
        float2 v = __half22float2(gp[(size_t)s * 32 + hl]);
        a1.x += v.x; a1.y += v.y;
      }
    }
  }

  float rx = (a0.x + a1.x) + (a2.x + a3.x);
  float ry = (a0.y + a1.y) + (a2.y + a3.y);
  rx += __shfl_xor(rx, 32);
  ry += __shfl_xor(ry, 32);
  if (half == 0) {
    float dn = dinv[wid];
    float2 bb = *(const float2*)(b + 2 * hl);
    *(float2*)(o + (size_t)wid * COUT + 2 * hl) =
        make_float2(fmaf(dn, rx, bb.x), fmaf(dn, ry, bb.y));
  }
}

// ---------------- launch ----------------

extern "C" void kernel_launch(void* const* d_in, const int* in_sizes, int n_in,
                              void* d_out, int out_size, void* d_ws, size_t ws_size,
                              hipStream_t stream) {
  const float* x  = (const float*)d_in[0];
  const int*   ei = (const int*)d_in[1];
  const float* W1 = (const float*)d_in[2];
  const float* b1 = (const float*)d_in[3];
  const float* W2 = (const float*)d_in[4];
  const float* b2 = (const float*)d_in[5];
  float* out = (float*)d_out;

  const int* esrc = ei;
  const int* edst = ei + NE;

  char* p = (char*)d_ws;
  __half* g1 = (__half*)p;    p += (size_t)NN * CHID * 2;   // 25.6 MB
  __half* o1 = (__half*)p;    p += (size_t)NN * CHID * 2;   // 25.6 MB
  __half* g2 = (__half*)p;    p += (size_t)NN * COUT * 2;   // 12.8 MB
  int* rs  = (int*)p;         p += (size_t)(NN + 1) * 4;
  float* dinv = (float*)p;    p += (size_t)NN * 4;
  int* tab = (int*)p;         p += (size_t)NB * NBLK * 4;   // 200 KB
  int* bb  = (int*)p;         p += (size_t)(NB + 1) * 4;
  int* barr = (int*)p;        p += (size_t)NE * 4;          // 6.4 MB
  int* csr = (int*)p;         p += (size_t)NE * 4;          // 6.4 MB

  // CSR build (two-level partition, write-combine friendly)
  hipLaunchKernelGGL(k_passA, dim3(NBLK), dim3(512), 0, stream, edst, tab);
  hipLaunchKernelGGL(k_bscan, dim3(1), dim3(512), 0, stream, tab, bb);
  hipLaunchKernelGGL(k_tabscan, dim3(NB), dim3(128), 0, stream, tab, bb);
  hipLaunchKernelGGL(k_passB, dim3(NBLK), dim3(512), 0, stream, esrc, edst, tab, barr);
  hipLaunchKernelGGL(k_l2, dim3(NB), dim3(256), 0, stream, barr, bb, csr, rs, dinv);

  // layer 1
  hipLaunchKernelGGL(k_gemm1, dim3(GGRID), dim3(256), 0, stream, x, W1, dinv, g1);
  hipLaunchKernelGGL(k_agg1, dim3((NN + 3) / 4), dim3(256), 0, stream, g1, rs, csr, dinv, b1, o1);

  // layer 2
  hipLaunchKernelGGL(k_gemm2, dim3(GGRID), dim3(256), 0, stream, o1, W2, dinv, g2);
  hipLaunchKernelGGL(k_agg2, dim3((NN + 3) / 4), dim3(256), 0, stream, g2, rs, csr, dinv, b2, out);
}